// Round 1
// baseline (3512.026 us; speedup 1.0000x reference)
//
#include <hip/hip_runtime.h>
#include <cstddef>

#define NCELL 100000
#define NNZE  800000
#define HID   128
#define CIN   64

// ============================ CSR build =================================
__global__ __launch_bounds__(256) void hist_kernel(const int* __restrict__ key,
                                                   int* __restrict__ counts) {
  int i = blockIdx.x * 256 + threadIdx.x;
  if (i < NNZE) atomicAdd(&counts[key[i]], 1);
}

// chunk = 2048 elements per block (256 thr x 8)
__global__ __launch_bounds__(256) void scan_partial(const int* __restrict__ counts,
                                                    int* __restrict__ bsum) {
  __shared__ int sdata[256];
  int t = threadIdx.x;
  int base = blockIdx.x * 2048;
  int s = 0;
  for (int j = 0; j < 8; ++j) {
    int i = base + j * 256 + t;
    if (i < NCELL) s += counts[i];
  }
  sdata[t] = s;
  __syncthreads();
  for (int off = 128; off > 0; off >>= 1) {
    if (t < off) sdata[t] += sdata[t + off];
    __syncthreads();
  }
  if (t == 0) bsum[blockIdx.x] = sdata[0];
}

__global__ __launch_bounds__(64) void scan_bsum(int* __restrict__ bsum, int nblk) {
  int l = threadIdx.x;
  int orig = (l < nblk) ? bsum[l] : 0;
  int v = orig;
  for (int off = 1; off < 64; off <<= 1) {
    int w = __shfl_up(v, off);
    if (l >= off) v += w;
  }
  if (l < nblk) bsum[l] = v - orig;  // exclusive
}

// cursor may alias counts: all reads of counts happen before first barrier,
// all writes after it; chunks are block-disjoint.
__global__ __launch_bounds__(256) void scan_final(const int* __restrict__ counts,
                                                  const int* __restrict__ bsum,
                                                  int* __restrict__ row_ptr,
                                                  int* __restrict__ cursor) {
  __shared__ int ss[256];
  int t = threadIdx.x;
  int base = blockIdx.x * 2048 + t * 8;
  int x[8];
  int ts = 0;
  for (int j = 0; j < 8; ++j) {
    int i = base + j;
    x[j] = (i < NCELL) ? counts[i] : 0;
    ts += x[j];
  }
  ss[t] = ts;
  __syncthreads();
  for (int off = 1; off < 256; off <<= 1) {
    int v = (t >= off) ? ss[t - off] : 0;
    __syncthreads();
    ss[t] += v;
    __syncthreads();
  }
  int offset = bsum[blockIdx.x] + ss[t] - ts;
  for (int j = 0; j < 8; ++j) {
    int i = base + j;
    if (i < NCELL) { row_ptr[i] = offset; cursor[i] = offset; }
    offset += x[j];
  }
  if (blockIdx.x == 0 && t == 0) row_ptr[NCELL] = NNZE;
}

__global__ __launch_bounds__(256) void scatter_kernel(const int* __restrict__ key,
                                                      const int* __restrict__ other,
                                                      const float* __restrict__ v,
                                                      int* __restrict__ cursor,
                                                      int* __restrict__ ocols,
                                                      float* __restrict__ ovals) {
  int i = blockIdx.x * 256 + threadIdx.x;
  if (i < NNZE) {
    int k = key[i];
    int pos = atomicAdd(&cursor[k], 1);
    ocols[pos] = other[i];
    ovals[pos] = v[i];
  }
}

// ============================ SpMM (CSR) ================================
// one wave per output row; lane l owns float2 cols [2l, 2l+1]
template <bool ACCUM>
__global__ __launch_bounds__(256) void spmm_csr(const int* __restrict__ row_ptr,
                                                const int* __restrict__ cols,
                                                const float* __restrict__ vals,
                                                const float* __restrict__ x,
                                                float* __restrict__ out, float scale) {
  int wid = (blockIdx.x * 256 + threadIdx.x) >> 6;
  int lane = threadIdx.x & 63;
  if (wid >= NCELL) return;
  int s = row_ptr[wid], e = row_ptr[wid + 1];
  const float2* x2 = (const float2*)x;
  float ax = 0.f, ay = 0.f;
  int i = s;
  for (; i + 4 <= e; i += 4) {  // 4 independent gathers in flight
    int c0 = cols[i], c1 = cols[i + 1], c2 = cols[i + 2], c3 = cols[i + 3];
    float v0 = vals[i], v1 = vals[i + 1], v2 = vals[i + 2], v3 = vals[i + 3];
    float2 g0 = x2[(size_t)c0 * 64 + lane];
    float2 g1 = x2[(size_t)c1 * 64 + lane];
    float2 g2 = x2[(size_t)c2 * 64 + lane];
    float2 g3 = x2[(size_t)c3 * 64 + lane];
    ax += v0 * g0.x + v1 * g1.x + v2 * g2.x + v3 * g3.x;
    ay += v0 * g0.y + v1 * g1.y + v2 * g2.y + v3 * g3.y;
  }
  for (; i < e; ++i) {
    int c = cols[i];
    float v = vals[i];
    float2 g = x2[(size_t)c * 64 + lane];
    ax += v * g.x;
    ay += v * g.y;
  }
  float2* o2 = (float2*)out;
  size_t oi = (size_t)wid * 64 + lane;
  if (ACCUM) {
    float2 cur = o2[oi];
    cur.x += scale * ax;
    cur.y += scale * ay;
    o2[oi] = cur;
  } else {
    o2[oi] = make_float2(scale * ax, scale * ay);
  }
}

// ============================ GEMMs =====================================
// out[N,128] = x[N,64] @ W[64,128] + b ; 8 rows/block, thread = (row, col4)
__global__ __launch_bounds__(256) void gemm_nc(const float* __restrict__ x,
                                               const float* __restrict__ W,
                                               const float* __restrict__ b,
                                               float* __restrict__ out) {
  __shared__ float xs[8][64];
  int t = threadIdx.x;
  int row0 = blockIdx.x * 8;
  for (int j = t; j < 512; j += 256) {
    int r = j >> 6, c = j & 63;
    xs[r][c] = x[(size_t)(row0 + r) * 64 + c];
  }
  __syncthreads();
  int tx = t & 31, ty = t >> 5;
  const float4* W4 = (const float4*)W;  // [64][32]
  float4 acc = {0.f, 0.f, 0.f, 0.f};
  for (int k = 0; k < 64; ++k) {
    float xv = xs[ty][k];
    float4 w = W4[k * 32 + tx];
    acc.x += xv * w.x; acc.y += xv * w.y; acc.z += xv * w.z; acc.w += xv * w.w;
  }
  float4 bb = ((const float4*)b)[tx];
  acc.x += bb.x; acc.y += bb.y; acc.z += bb.z; acc.w += bb.w;
  ((float4*)out)[(size_t)(row0 + ty) * 32 + tx] = acc;
}

// out[N,128] = act(x[N,128] @ W[128,128] + b) ; PRELU optional
template <bool PRELU>
__global__ __launch_bounds__(256) void gemm_hh(const float* __restrict__ x,
                                               const float* __restrict__ W,
                                               const float* __restrict__ b,
                                               const float* __restrict__ alpha,
                                               float* __restrict__ out) {
  __shared__ float xs[8][128];
  int t = threadIdx.x;
  int row0 = blockIdx.x * 8;
  for (int j = t; j < 1024; j += 256) {
    int r = j >> 7, c = j & 127;
    xs[r][c] = x[(size_t)(row0 + r) * 128 + c];
  }
  __syncthreads();
  int tx = t & 31, ty = t >> 5;
  const float4* W4 = (const float4*)W;  // [128][32]
  float4 acc = {0.f, 0.f, 0.f, 0.f};
  for (int k = 0; k < 128; ++k) {
    float xv = xs[ty][k];
    float4 w = W4[k * 32 + tx];
    acc.x += xv * w.x; acc.y += xv * w.y; acc.z += xv * w.z; acc.w += xv * w.w;
  }
  float4 bb = ((const float4*)b)[tx];
  acc.x += bb.x; acc.y += bb.y; acc.z += bb.z; acc.w += bb.w;
  if (PRELU) {
    float a = alpha[0];
    acc.x = acc.x >= 0.f ? acc.x : a * acc.x;
    acc.y = acc.y >= 0.f ? acc.y : a * acc.y;
    acc.z = acc.z >= 0.f ? acc.z : a * acc.z;
    acc.w = acc.w >= 0.f ? acc.w : a * acc.w;
  }
  ((float4*)out)[(size_t)(row0 + ty) * 32 + tx] = acc;
}

// ======================== sigmoid gate + mean ===========================
// out[row] (+)= (sigmoid(comb[row].a)/3) * comb[row] ; one wave per row
template <bool FIRST>
__global__ __launch_bounds__(256) void gate_out(const float* __restrict__ comb,
                                                const float* __restrict__ a,
                                                float* __restrict__ out) {
  int wid = (blockIdx.x * 256 + threadIdx.x) >> 6;
  int lane = threadIdx.x & 63;
  if (wid >= NCELL) return;
  const float2* c2 = (const float2*)comb;
  float2 cv = c2[(size_t)wid * 64 + lane];
  float2 avv = ((const float2*)a)[lane];
  float d = cv.x * avv.x + cv.y * avv.y;
  for (int off = 32; off > 0; off >>= 1) d += __shfl_xor(d, off);
  float g = (1.0f / (1.0f + expf(-d))) * (1.0f / 3.0f);
  float2* o2 = (float2*)out;
  size_t oi = (size_t)wid * 64 + lane;
  if (FIRST) {
    o2[oi] = make_float2(g * cv.x, g * cv.y);
  } else {
    float2 cur = o2[oi];
    cur.x += g * cv.x;
    cur.y += g * cv.y;
    o2[oi] = cur;
  }
}

// ============================ driver ====================================
extern "C" void kernel_launch(void* const* d_in, const int* in_sizes, int n_in,
                              void* d_out, int out_size, void* d_ws, size_t ws_size,
                              hipStream_t stream) {
  const float* x[3] = {(const float*)d_in[0], (const float*)d_in[1], (const float*)d_in[2]};
  const int* kr[5]; const int* kc[5]; const float* kv[5];  // a0,a1,a2,b1,b2
  for (int m = 0; m < 5; ++m) {
    kr[m] = (const int*)d_in[3 + 3 * m];
    kc[m] = (const int*)d_in[4 + 3 * m];
    kv[m] = (const float*)d_in[5 + 3 * m];
  }
  const float *W[2][3], *bv[2][3], *av[2][3];
  int idx = 18;
  for (int e = 0; e < 2; ++e)
    for (int d = 0; d < 3; ++d) {
      W[e][d]  = (const float*)d_in[idx++];
      bv[e][d] = (const float*)d_in[idx++];
      av[e][d] = (const float*)d_in[idx++];
    }
  const float* pW1   = (const float*)d_in[36];
  const float* pb1   = (const float*)d_in[37];
  const float* alpha = (const float*)d_in[38];
  const float* pW2   = (const float*)d_in[39];
  const float* pb2   = (const float*)d_in[40];

  float* out = (float*)d_out;
  const size_t NH = (size_t)NCELL * HID;
  float* h_online = out;
  float* h_pred   = out + NH;
  float* h_target = out + 2 * NH;

  char* w = (char*)d_ws;
  auto carve = [&](size_t bytes) -> void* {
    void* p = (void*)w;
    w += (bytes + 255) & ~(size_t)255;
    return p;
  };
  float* xt   = (float*)carve(NH * 4);
  float* tmp  = (float*)carve(NH * 4);
  float* comb = h_pred;  // reuse output slot 1 as scratch until final GEMM
  int* rowp[7]; int* ccol[7]; float* cval[7];
  for (int s = 0; s < 7; ++s) {
    rowp[s] = (int*)carve((size_t)(NCELL + 1) * 4);
    ccol[s] = (int*)carve((size_t)NNZE * 4);
    cval[s] = (float*)carve((size_t)NNZE * 4);
  }
  int* counts = (int*)carve((size_t)NCELL * 4);  // also the scatter cursor
  int* bsum   = (int*)carve(64 * 4);

  // CSR structures: 0..2 = A_d keyed by r; 3/4 = B1 by r / by c; 5/6 = B2 by r / by c
  const int*   skey[7] = {kr[0], kr[1], kr[2], kr[3], kc[3], kr[4], kc[4]};
  const int*   soth[7] = {kc[0], kc[1], kc[2], kc[3], kr[3], kc[4], kr[4]};
  const float* sval[7] = {kv[0], kv[1], kv[2], kv[3], kv[3], kv[4], kv[4]};

  for (int s = 0; s < 7; ++s) {
    hipMemsetAsync(counts, 0, (size_t)NCELL * 4, stream);
    hist_kernel<<<3125, 256, 0, stream>>>(skey[s], counts);
    scan_partial<<<49, 256, 0, stream>>>(counts, bsum);
    scan_bsum<<<1, 64, 0, stream>>>(bsum, 49);
    scan_final<<<49, 256, 0, stream>>>(counts, bsum, rowp[s], counts);
    scatter_kernel<<<3125, 256, 0, stream>>>(skey[s], soth[s], sval[s], counts, ccol[s], cval[s]);
  }

  for (int e = 0; e < 2; ++e) {
    float* hout = e ? h_target : h_online;
    for (int d = 0; d < 3; ++d) {
      gemm_nc<<<12500, 256, 0, stream>>>(x[d], W[e][d], bv[e][d], xt);
      // same-dim messages: comb = A_d @ xt
      spmm_csr<false><<<25000, 256, 0, stream>>>(rowp[d], ccol[d], cval[d], xt, comb, 1.0f);
      // boundary down: d==1 -> B1, d==2 -> B2 : comb += 0.5 * B^T (B xt)
      if (d == 1 || d == 2) {
        int br = (d == 1) ? 3 : 5, bc = br + 1;
        spmm_csr<false><<<25000, 256, 0, stream>>>(rowp[br], ccol[br], cval[br], xt, tmp, 1.0f);
        spmm_csr<true><<<25000, 256, 0, stream>>>(rowp[bc], ccol[bc], cval[bc], tmp, comb, 0.5f);
      }
      // boundary up: d==0 -> B1, d==1 -> B2
      if (d == 0 || d == 1) {
        int br = (d == 0) ? 3 : 5, bc = br + 1;
        spmm_csr<false><<<25000, 256, 0, stream>>>(rowp[br], ccol[br], cval[br], xt, tmp, 1.0f);
        spmm_csr<true><<<25000, 256, 0, stream>>>(rowp[bc], ccol[bc], cval[bc], tmp, comb, 0.5f);
      }
      if (d == 0) gate_out<true><<<25000, 256, 0, stream>>>(comb, av[e][d], hout);
      else        gate_out<false><<<25000, 256, 0, stream>>>(comb, av[e][d], hout);
    }
  }

  // predictor: h1 = PReLU(h_online @ pW1 + pb1); h_pred = h1 @ pW2 + pb2
  gemm_hh<true><<<12500, 256, 0, stream>>>(h_online, pW1, pb1, alpha, tmp);
  gemm_hh<false><<<12500, 256, 0, stream>>>(tmp, pW2, pb2, alpha, h_pred);
}

// Round 2
// 2216.566 us; speedup vs baseline: 1.5844x; 1.5844x over previous
//
#include <hip/hip_runtime.h>
#include <cstddef>

#define NCELL 100000
#define NNZE  800000
#define HID   128
#define CIN   64
#define T7    (7 * NCELL)

struct P7i { const int* p[7]; };
struct P7f { const float* p[7]; };

__device__ __forceinline__ unsigned short f2bf(float f) {
  unsigned u = __float_as_uint(f);
  return (unsigned short)((u + 0x7fffu + ((u >> 16) & 1u)) >> 16);
}
__device__ __forceinline__ float bflo(unsigned x) { return __uint_as_float(x << 16); }
__device__ __forceinline__ float bfhi(unsigned x) { return __uint_as_float(x & 0xffff0000u); }
__device__ __forceinline__ void fma4(float4& a, float s, const float4& w) {
  a.x += s * w.x; a.y += s * w.y; a.z += s * w.z; a.w += s * w.w;
}

// ============================ CSR build (fused, all 7) ==================
__global__ __launch_bounds__(256) void hist_all(P7i keys, int* __restrict__ counts) {
  int s = blockIdx.y;
  int i = blockIdx.x * 256 + threadIdx.x;
  if (i < NNZE) atomicAdd(&counts[s * NCELL + keys.p[s][i]], 1);
}

// chunk = 16384 per block; 43 blocks cover 700000
__global__ __launch_bounds__(256) void scan_partial2(const int* __restrict__ counts,
                                                     int* __restrict__ bsum) {
  __shared__ int sdata[256];
  int t = threadIdx.x;
  int s = 0;
  for (int j = 0; j < 64; ++j) {
    int i = blockIdx.x * 16384 + j * 256 + t;
    if (i < T7) s += counts[i];
  }
  sdata[t] = s;
  __syncthreads();
  for (int off = 128; off > 0; off >>= 1) {
    if (t < off) sdata[t] += sdata[t + off];
    __syncthreads();
  }
  if (t == 0) bsum[blockIdx.x] = sdata[0];
}

__global__ __launch_bounds__(64) void scan_bsum(int* __restrict__ bsum, int nblk) {
  int l = threadIdx.x;
  int orig = (l < nblk) ? bsum[l] : 0;
  int v = orig;
  for (int off = 1; off < 64; off <<= 1) {
    int w = __shfl_up(v, off);
    if (l >= off) v += w;
  }
  if (l < nblk) bsum[l] = v - orig;  // exclusive
}

__global__ __launch_bounds__(256) void scan_final2(const int* __restrict__ counts,
                                                   const int* __restrict__ bsum,
                                                   int* __restrict__ rowp,
                                                   int* __restrict__ cursor) {
  __shared__ int ss[256];
  int t = threadIdx.x;
  int base = blockIdx.x * 16384 + t * 64;
  int ts = 0;
  for (int j = 0; j < 64; ++j) {
    int i = base + j;
    if (i < T7) ts += counts[i];
  }
  ss[t] = ts;
  __syncthreads();
  for (int off = 1; off < 256; off <<= 1) {
    int v = (t >= off) ? ss[t - off] : 0;
    __syncthreads();
    ss[t] += v;
    __syncthreads();
  }
  int offset = bsum[blockIdx.x] + ss[t] - ts;
  for (int j = 0; j < 64; ++j) {
    int i = base + j;
    if (i < T7) {
      rowp[i] = offset;
      cursor[i] = offset;
      offset += counts[i];
    }
  }
  if (blockIdx.x == 0 && t == 0) rowp[T7] = 7 * NNZE;
}

__global__ __launch_bounds__(256) void scatter_all(P7i keys, P7i oth, P7f vs,
                                                   int* __restrict__ cursor,
                                                   int* __restrict__ ocols,
                                                   float* __restrict__ ovals) {
  int s = blockIdx.y;
  int i = blockIdx.x * 256 + threadIdx.x;
  if (i < NNZE) {
    int k = keys.p[s][i];
    int pos = atomicAdd(&cursor[s * NCELL + k], 1);
    ocols[pos] = oth.p[s][i];
    ovals[pos] = vs.p[s][i];
  }
}

// ============================ SpMM width-256 (bf16 gathers) =============
// one wave per row; lane owns 4 bf16 cols (8B). MODE: 0=write bf16 outT,
// 1=write fp32 comb split by encoder, 2=accumulate 0.5x into comb split.
template <int MODE>
__global__ __launch_bounds__(256) void spmm256(const int* __restrict__ rowp,
                                               const int* __restrict__ cols,
                                               const float* __restrict__ vals,
                                               const uint2* __restrict__ xb,
                                               uint2* __restrict__ outT,
                                               float4* __restrict__ c0,
                                               float4* __restrict__ c1) {
  int wid = (blockIdx.x * 256 + threadIdx.x) >> 6;
  int lane = threadIdx.x & 63;
  int s = rowp[wid], e = rowp[wid + 1];
  float a0 = 0.f, a1 = 0.f, a2 = 0.f, a3 = 0.f;
  int i = s;
  for (; i + 4 <= e; i += 4) {
    int ci0 = cols[i], ci1 = cols[i + 1], ci2 = cols[i + 2], ci3 = cols[i + 3];
    float v0 = vals[i], v1 = vals[i + 1], v2 = vals[i + 2], v3 = vals[i + 3];
    uint2 g0 = xb[(size_t)ci0 * 64 + lane];
    uint2 g1 = xb[(size_t)ci1 * 64 + lane];
    uint2 g2 = xb[(size_t)ci2 * 64 + lane];
    uint2 g3 = xb[(size_t)ci3 * 64 + lane];
    a0 += v0 * bflo(g0.x); a1 += v0 * bfhi(g0.x); a2 += v0 * bflo(g0.y); a3 += v0 * bfhi(g0.y);
    a0 += v1 * bflo(g1.x); a1 += v1 * bfhi(g1.x); a2 += v1 * bflo(g1.y); a3 += v1 * bfhi(g1.y);
    a0 += v2 * bflo(g2.x); a1 += v2 * bfhi(g2.x); a2 += v2 * bflo(g2.y); a3 += v2 * bfhi(g2.y);
    a0 += v3 * bflo(g3.x); a1 += v3 * bfhi(g3.x); a2 += v3 * bflo(g3.y); a3 += v3 * bfhi(g3.y);
  }
  for (; i < e; ++i) {
    int c = cols[i];
    float v = vals[i];
    uint2 g = xb[(size_t)c * 64 + lane];
    a0 += v * bflo(g.x); a1 += v * bfhi(g.x); a2 += v * bflo(g.y); a3 += v * bfhi(g.y);
  }
  if (MODE == 0) {
    uint2 pk;
    pk.x = (unsigned)f2bf(a0) | ((unsigned)f2bf(a1) << 16);
    pk.y = (unsigned)f2bf(a2) | ((unsigned)f2bf(a3) << 16);
    outT[(size_t)wid * 64 + lane] = pk;
  } else {
    float4 v = make_float4(a0, a1, a2, a3);
    float4* dst = (lane < 32) ? (c0 + (size_t)wid * 32 + lane)
                              : (c1 + (size_t)wid * 32 + (lane - 32));
    if (MODE == 1) {
      *dst = v;
    } else {
      float4 cur = *dst;
      cur.x += 0.5f * v.x; cur.y += 0.5f * v.y;
      cur.z += 0.5f * v.z; cur.w += 0.5f * v.w;
      *dst = cur;
    }
  }
}

// ===================== fused input GEMM (both encoders) =================
// xt2[n][256] (bf16) = [ x[n]@W0+b0 | x[n]@W1+b1 ] ; 16 rows/block
__global__ __launch_bounds__(256) void gemm_nc2(const float* __restrict__ x,
                                                const float* __restrict__ W0,
                                                const float* __restrict__ b0,
                                                const float* __restrict__ W1,
                                                const float* __restrict__ b1,
                                                uint2* __restrict__ out) {
  __shared__ float xs[16][64];
  int t = threadIdx.x;
  int row0 = blockIdx.x * 16;
  ((float4*)xs)[t] = ((const float4*)x)[(size_t)row0 * 16 + t];
  __syncthreads();
  int tx = t & 31, ty = t >> 5;  // ty: rows ty and ty+8
  const float4* W0_4 = (const float4*)W0;
  const float4* W1_4 = (const float4*)W1;
  float4 a00 = {0, 0, 0, 0}, a01 = {0, 0, 0, 0}, a10 = {0, 0, 0, 0}, a11 = {0, 0, 0, 0};
#pragma unroll 8
  for (int k = 0; k < 64; ++k) {
    float xv0 = xs[ty][k];
    float xv1 = xs[ty + 8][k];
    float4 w0 = W0_4[k * 32 + tx];
    float4 w1 = W1_4[k * 32 + tx];
    fma4(a00, xv0, w0); fma4(a01, xv1, w0);
    fma4(a10, xv0, w1); fma4(a11, xv1, w1);
  }
  float4 bb0 = ((const float4*)b0)[tx];
  float4 bb1 = ((const float4*)b1)[tx];
  fma4(a00, 1.f, bb0); fma4(a01, 1.f, bb0);
  fma4(a10, 1.f, bb1); fma4(a11, 1.f, bb1);
  auto pack = [](const float4& v) {
    uint2 p;
    p.x = (unsigned)f2bf(v.x) | ((unsigned)f2bf(v.y) << 16);
    p.y = (unsigned)f2bf(v.z) | ((unsigned)f2bf(v.w) << 16);
    return p;
  };
  size_t r0 = (size_t)(row0 + ty) * 64;
  size_t r1 = (size_t)(row0 + ty + 8) * 64;
  out[r0 + tx] = pack(a00);
  out[r0 + 32 + tx] = pack(a10);
  out[r1 + tx] = pack(a01);
  out[r1 + 32 + tx] = pack(a11);
}

// ===================== H x H GEMM, LDS-tiled =============================
// out[N,128] = act(x[N,128] @ W[128,128] + b); 32 rows/block, 16 acc/thread
template <bool PRELU>
__global__ __launch_bounds__(256) void gemm_hh2(const float* __restrict__ x,
                                                const float* __restrict__ W,
                                                const float* __restrict__ b,
                                                const float* __restrict__ alpha,
                                                float* __restrict__ out) {
  __shared__ float As[32 * 36];   // [k][m], padded
  __shared__ float Ws[32 * 128];  // [k][n]
  int t = threadIdx.x;
  int tx = t & 31, ty = t >> 5;  // cols 4tx.., rows ty*4..
  int row0 = blockIdx.x * 32;
  float4 acc[4] = {{0, 0, 0, 0}, {0, 0, 0, 0}, {0, 0, 0, 0}, {0, 0, 0, 0}};
  const float4* Wg4 = (const float4*)W;
  for (int kt = 0; kt < 4; ++kt) {
    __syncthreads();
    {  // stage A tile transposed: As[k][m]
      int r = t >> 3;    // 0..31 (row within tile)
      int c4 = t & 7;    // 0..7  (float4 within 32-k slice)
      float4 av = ((const float4*)(x + (size_t)(row0 + r) * 128 + kt * 32))[c4];
      As[(c4 * 4 + 0) * 36 + r] = av.x;
      As[(c4 * 4 + 1) * 36 + r] = av.y;
      As[(c4 * 4 + 2) * 36 + r] = av.z;
      As[(c4 * 4 + 3) * 36 + r] = av.w;
    }
    {  // stage W tile: Ws[k][n]
#pragma unroll
      for (int j = 0; j < 4; ++j) {
        int idx = j * 256 + t;
        ((float4*)Ws)[idx] = Wg4[kt * 1024 + idx];
      }
    }
    __syncthreads();
#pragma unroll
    for (int k = 0; k < 32; ++k) {
      float4 am = *(const float4*)&As[k * 36 + ty * 4];
      float4 w4 = ((const float4*)Ws)[k * 32 + tx];
      fma4(acc[0], am.x, w4);
      fma4(acc[1], am.y, w4);
      fma4(acc[2], am.z, w4);
      fma4(acc[3], am.w, w4);
    }
  }
  float4 bb = ((const float4*)b)[tx];
  float al = PRELU ? alpha[0] : 0.f;
#pragma unroll
  for (int r = 0; r < 4; ++r) {
    float4 v = acc[r];
    v.x += bb.x; v.y += bb.y; v.z += bb.z; v.w += bb.w;
    if (PRELU) {
      v.x = v.x >= 0.f ? v.x : al * v.x;
      v.y = v.y >= 0.f ? v.y : al * v.y;
      v.z = v.z >= 0.f ? v.z : al * v.z;
      v.w = v.w >= 0.f ? v.w : al * v.w;
    }
    ((float4*)out)[(size_t)(row0 + ty * 4 + r) * 32 + tx] = v;
  }
}

// ======================== sigmoid gate + mean (both e) ==================
__global__ __launch_bounds__(256) void gate2(const float4* __restrict__ c0,
                                             const float4* __restrict__ c1,
                                             const float4* __restrict__ a0,
                                             const float4* __restrict__ a1,
                                             float4* __restrict__ hon,
                                             float4* __restrict__ htg, int first) {
  int wid = (blockIdx.x * 256 + threadIdx.x) >> 6;
  int lane = threadIdx.x & 63;
  bool e1 = lane >= 32;
  int l = lane & 31;
  const float4* cb = e1 ? c1 : c0;
  float4 cv = cb[(size_t)wid * 32 + l];
  float4 av = (e1 ? a1 : a0)[l];
  float d = cv.x * av.x + cv.y * av.y + cv.z * av.z + cv.w * av.w;
  d += __shfl_xor(d, 16);
  d += __shfl_xor(d, 8);
  d += __shfl_xor(d, 4);
  d += __shfl_xor(d, 2);
  d += __shfl_xor(d, 1);
  float g = (1.f / (1.f + __expf(-d))) * (1.f / 3.f);
  float4* hb = e1 ? htg : hon;
  size_t oi = (size_t)wid * 32 + l;
  float4 v = make_float4(g * cv.x, g * cv.y, g * cv.z, g * cv.w);
  if (first) {
    hb[oi] = v;
  } else {
    float4 cur = hb[oi];
    cur.x += v.x; cur.y += v.y; cur.z += v.z; cur.w += v.w;
    hb[oi] = cur;
  }
}

// ============================ driver ====================================
extern "C" void kernel_launch(void* const* d_in, const int* in_sizes, int n_in,
                              void* d_out, int out_size, void* d_ws, size_t ws_size,
                              hipStream_t stream) {
  const float* x[3] = {(const float*)d_in[0], (const float*)d_in[1], (const float*)d_in[2]};
  const int* kr[5]; const int* kc[5]; const float* kv[5];  // a0,a1,a2,b1,b2
  for (int m = 0; m < 5; ++m) {
    kr[m] = (const int*)d_in[3 + 3 * m];
    kc[m] = (const int*)d_in[4 + 3 * m];
    kv[m] = (const float*)d_in[5 + 3 * m];
  }
  const float *W[2][3], *bv[2][3], *av[2][3];
  int idx = 18;
  for (int e = 0; e < 2; ++e)
    for (int d = 0; d < 3; ++d) {
      W[e][d] = (const float*)d_in[idx++];
      bv[e][d] = (const float*)d_in[idx++];
      av[e][d] = (const float*)d_in[idx++];
    }
  const float* pW1 = (const float*)d_in[36];
  const float* pb1 = (const float*)d_in[37];
  const float* alpha = (const float*)d_in[38];
  const float* pW2 = (const float*)d_in[39];
  const float* pb2 = (const float*)d_in[40];

  float* out = (float*)d_out;
  const size_t NH = (size_t)NCELL * HID;
  float* h_online = out;
  float* h_pred = out + NH;    // doubles as comb_e0 scratch until final GEMM
  float* h_target = out + 2 * NH;

  char* w = (char*)d_ws;
  auto carve = [&](size_t bytes) -> void* {
    void* p = (void*)w;
    w += (bytes + 255) & ~(size_t)255;
    return p;
  };
  int* rowp_g = (int*)carve((size_t)(T7 + 1) * 4);       // 2.8 MB
  int* cols_g = (int*)carve((size_t)7 * NNZE * 4);       // 22.4 MB
  float* vals_g = (float*)carve((size_t)7 * NNZE * 4);   // 22.4 MB
  int* counts = (int*)carve((size_t)T7 * 4);             // 2.8 MB
  int* cursor = (int*)carve((size_t)T7 * 4);             // 2.8 MB
  uint2* xt2 = (uint2*)carve((size_t)NCELL * 256 * 2);   // 51.2 MB (bf16)
  uint2* t2 = (uint2*)carve((size_t)NCELL * 256 * 2);    // 51.2 MB (bf16)
  float* comb1 = (float*)carve(NH * 4);                  // 51.2 MB (fp32, e1)
  int* bsum = (int*)carve(64 * 4);
  float* comb0 = h_pred;

  // structures: 0..2 = A_d (by r); 3/4 = B1 by r / by c; 5/6 = B2 by r / by c
  P7i skey = {{kr[0], kr[1], kr[2], kr[3], kc[3], kr[4], kc[4]}};
  P7i soth = {{kc[0], kc[1], kc[2], kc[3], kr[3], kc[4], kr[4]}};
  P7f sval = {{kv[0], kv[1], kv[2], kv[3], kv[3], kv[4], kv[4]}};

  hipMemsetAsync(counts, 0, (size_t)T7 * 4, stream);
  hist_all<<<dim3(3125, 7), 256, 0, stream>>>(skey, counts);
  scan_partial2<<<43, 256, 0, stream>>>(counts, bsum);
  scan_bsum<<<1, 64, 0, stream>>>(bsum, 43);
  scan_final2<<<43, 256, 0, stream>>>(counts, bsum, rowp_g, cursor);
  scatter_all<<<dim3(3125, 7), 256, 0, stream>>>(skey, soth, sval, cursor, cols_g, vals_g);

  static const int nB[3] = {1, 2, 1};
  static const int BS[3][2] = {{3, -1}, {3, 5}, {5, -1}};
  for (int d = 0; d < 3; ++d) {
    gemm_nc2<<<6250, 256, 0, stream>>>(x[d], W[0][d], bv[0][d], W[1][d], bv[1][d], xt2);
    spmm256<1><<<25000, 256, 0, stream>>>(rowp_g + d * NCELL, cols_g, vals_g, xt2,
                                          nullptr, (float4*)comb0, (float4*)comb1);
    for (int bi = 0; bi < nB[d]; ++bi) {
      int sR = BS[d][bi];
      spmm256<0><<<25000, 256, 0, stream>>>(rowp_g + sR * NCELL, cols_g, vals_g, xt2,
                                            t2, nullptr, nullptr);
      spmm256<2><<<25000, 256, 0, stream>>>(rowp_g + (sR + 1) * NCELL, cols_g, vals_g, t2,
                                            nullptr, (float4*)comb0, (float4*)comb1);
    }
    gate2<<<25000, 256, 0, stream>>>((const float4*)comb0, (const float4*)comb1,
                                     (const float4*)av[0][d], (const float4*)av[1][d],
                                     (float4*)h_online, (float4*)h_target, d == 0 ? 1 : 0);
  }

  float* tmpf = (float*)t2;  // t2 dead; reuse as fp32 [N,128]
  gemm_hh2<true><<<3125, 256, 0, stream>>>(h_online, pW1, pb1, alpha, tmpf);
  gemm_hh2<false><<<3125, 256, 0, stream>>>(tmpf, pW2, pb2, alpha, h_pred);
}